// Round 7
// baseline (856.223 us; speedup 1.0000x reference)
//
#include <hip/hip_runtime.h>
#include <hip/hip_fp16.h>

#define NNODES 60000
#define NEDGES 960000
#define NGRAPH 10000

struct __align__(16) H8 { __half2 h[4]; };
struct __align__(8)  H4 { __half2 h[2]; };

typedef _Float16 f16x8 __attribute__((ext_vector_type(8)));
typedef float f32x4 __attribute__((ext_vector_type(4)));

// ---------------- degree / CSR build ----------------

__global__ void count_deg_k(const int* __restrict__ ei, int* __restrict__ deg) {
  int e = blockIdx.x * blockDim.x + threadIdx.x;
  atomicAdd(&deg[ei[NEDGES + e]], 1);
}

// scan1 also produces dinv = rsqrt(deg+1)
__global__ void scan1_k(const int* __restrict__ deg, int* __restrict__ rs,
                        int* __restrict__ bsum, float* __restrict__ dinv) {
  __shared__ int s[256];
  int tid = threadIdx.x;
  int i = blockIdx.x * 256 + tid;
  int v = (i < NNODES) ? deg[i] : 0;
  if (i < NNODES) dinv[i] = rsqrtf((float)v + 1.0f);
  int x = v;
  s[tid] = x; __syncthreads();
  #pragma unroll
  for (int off = 1; off < 256; off <<= 1) {
    int t = (tid >= off) ? s[tid - off] : 0;
    __syncthreads();
    x += t; s[tid] = x; __syncthreads();
  }
  if (i < NNODES) rs[i] = x - v;
  if (tid == 255) bsum[blockIdx.x] = x;
}

__global__ void scan2_k(int* __restrict__ bsum, int nb) {
  __shared__ int s[256];
  int tid = threadIdx.x;
  int v = (tid < nb) ? bsum[tid] : 0;
  int x = v; s[tid] = x; __syncthreads();
  #pragma unroll
  for (int off = 1; off < 256; off <<= 1) {
    int t = (tid >= off) ? s[tid - off] : 0;
    __syncthreads();
    x += t; s[tid] = x; __syncthreads();
  }
  if (tid < nb) bsum[tid] = x - v;
}

__global__ void scan3_k(int* __restrict__ rs, const int* __restrict__ bsum) {
  int i = blockIdx.x * 256 + threadIdx.x;
  if (i < NNODES) rs[i] += bsum[blockIdx.x];
  if (i == 0) rs[NNODES] = NEDGES;
}

__global__ void scatter_k(const int* __restrict__ ei, const int* __restrict__ rs,
                          int* __restrict__ cursor, unsigned short* __restrict__ csr) {
  int e = blockIdx.x * blockDim.x + threadIdx.x;
  int s = ei[e], d = ei[NEDGES + e];
  int pos = rs[d] + atomicAdd(&cursor[d], 1);
  csr[pos] = (unsigned short)s;
}

// ---------------- fused: state fp32->fp16 + part5 = state @ lw6 ----------------

__launch_bounds__(256)
__global__ void f2hskern_k(const float* __restrict__ state, const float* __restrict__ lw,
                           __half* __restrict__ stateh, float* __restrict__ part) {
  __shared__ float os[32][256];
  int tid = threadIdx.x;
  int n0 = blockIdx.x * 32;
  #pragma unroll
  for (int l = 0; l < 4; ++l) {
    int f = tid + l * 256;
    int row = f >> 5, c8 = (f & 31) * 8;
    const float* src = state + (size_t)(n0 + row) * 256 + c8;
    float4 u = *reinterpret_cast<const float4*>(src);
    float4 v = *reinterpret_cast<const float4*>(src + 4);
    float* dst = &os[row][c8];
    dst[0] = u.x; dst[1] = u.y; dst[2] = u.z; dst[3] = u.w;
    dst[4] = v.x; dst[5] = v.y; dst[6] = v.z; dst[7] = v.w;
    H8 o;
    o.h[0].x = __float2half_rn(u.x); o.h[0].y = __float2half_rn(u.y);
    o.h[1].x = __float2half_rn(u.z); o.h[1].y = __float2half_rn(u.w);
    o.h[2].x = __float2half_rn(v.x); o.h[2].y = __float2half_rn(v.y);
    o.h[3].x = __float2half_rn(v.z); o.h[3].y = __float2half_rn(v.w);
    *reinterpret_cast<H8*>(stateh + (size_t)(n0 + row) * 256 + c8) = o;
  }
  __syncthreads();
  int dim = tid & 31, rblk = tid >> 5;
  float a0 = 0.f, a1 = 0.f, a2 = 0.f, a3 = 0.f;
  #pragma unroll 8
  for (int k = 0; k < 256; ++k) {
    float w = lw[k * 32 + dim];
    a0 += os[rblk * 4 + 0][k] * w;
    a1 += os[rblk * 4 + 1][k] * w;
    a2 += os[rblk * 4 + 2][k] * w;
    a3 += os[rblk * 4 + 3][k] * w;
  }
  int base = (n0 + rblk * 4) * 32 + dim;
  part[base] = a0;
  part[base + 32] = a1;
  part[base + 64] = a2;
  part[base + 96] = a3;
}

// ---------------- weight transpose+convert ----------------

__global__ void wconv3_k(const float* __restrict__ W1, const float* __restrict__ W2,
                         const float* __restrict__ W3, __half* __restrict__ T1,
                         __half* __restrict__ T2, __half* __restrict__ T3) {
  int n = blockIdx.x & 255, which = blockIdx.x >> 8, k = threadIdx.x;
  const float* W = which == 0 ? W1 : (which == 1 ? W2 : W3);
  __half* T = which == 0 ? T1 : (which == 1 ? T2 : T3);
  T[n * 256 + k] = __float2half_rn(W[k * 256 + n]);
}

// ---------------- MFMA GEMM: Y[r] = fp16((X @ W)[r] * dinv[r]) ----------------
// 64x256 tile, 938 blocks. A-tile staged ONCE (33.8 KB LDS), B-frags read directly
// from global (W is L2-resident, 128 KB). One barrier total; K-loop barrier-free.
// 4 waves 2x2: wave = 32 rows x 128 cols = 2x8 frags of 16x16x32 f16 (swapped ops).

#define LDA 264   // halves; 528 B row stride

__launch_bounds__(256, 3)
__global__ void gemm_mfma_k(const __half* __restrict__ Xh, const __half* __restrict__ WhT,
                            const float* __restrict__ dinv, __half* __restrict__ Y) {
  __shared__ _Float16 As[64][LDA];
  const int tid = threadIdx.x;
  const int m0 = blockIdx.x * 64;
  const int lane = tid & 63;
  const int wid = tid >> 6;
  const int wr = wid >> 1, wc = wid & 1;
  const int li = lane & 15, lg = lane >> 4;

  // stage A: 64 rows x 256 halves = 2048 H8 units, 8 per thread
  #pragma unroll
  for (int l = 0; l < 8; ++l) {
    int f = l * 256 + tid;
    int row = f >> 5, c8 = (f & 31) * 8;
    int gr = m0 + row; if (gr >= NNODES) gr = NNODES - 1;
    *reinterpret_cast<H8*>(&As[row][c8]) =
        *reinterpret_cast<const H8*>(Xh + (size_t)gr * 256 + c8);
  }
  __syncthreads();

  f32x4 acc[2][8];
  #pragma unroll
  for (int i = 0; i < 2; ++i)
    #pragma unroll
    for (int j = 0; j < 8; ++j) acc[i][j] = (f32x4){0.f, 0.f, 0.f, 0.f};

  #pragma unroll
  for (int k0 = 0; k0 < 256; k0 += 32) {
    f16x8 a0 = *reinterpret_cast<const f16x8*>(&As[wr * 32 + li][k0 + lg * 8]);
    f16x8 a1 = *reinterpret_cast<const f16x8*>(&As[wr * 32 + 16 + li][k0 + lg * 8]);
    f16x8 b[8];
    #pragma unroll
    for (int cf = 0; cf < 8; ++cf)
      b[cf] = *reinterpret_cast<const f16x8*>(
          WhT + (size_t)(wc * 128 + cf * 16 + li) * 256 + k0 + lg * 8);
    #pragma unroll
    for (int cf = 0; cf < 8; ++cf) {
      acc[0][cf] = __builtin_amdgcn_mfma_f32_16x16x32_f16(b[cf], a0, acc[0][cf], 0, 0, 0);
      acc[1][cf] = __builtin_amdgcn_mfma_f32_16x16x32_f16(b[cf], a1, acc[1][cf], 0, 0, 0);
    }
  }

  #pragma unroll
  for (int rf = 0; rf < 2; ++rf) {
    int r = m0 + wr * 32 + rf * 16 + li;
    if (r < NNODES) {
      float dv = dinv[r];
      #pragma unroll
      for (int cf = 0; cf < 8; ++cf) {
        int n = wc * 128 + cf * 16 + lg * 4;
        H4 o;
        o.h[0].x = __float2half_rn(acc[rf][cf][0] * dv);
        o.h[0].y = __float2half_rn(acc[rf][cf][1] * dv);
        o.h[1].x = __float2half_rn(acc[rf][cf][2] * dv);
        o.h[1].y = __float2half_rn(acc[rf][cf][3] * dv);
        *reinterpret_cast<H4*>(Y + (size_t)r * 256 + n) = o;
      }
    }
  }
}

// ---------------- fused gather + skern ----------------
// phase 1: o[d] = relu(dinv*(ys[d]+sum ys[src])+b) -> obufh (fp16) + LDS (fp32)
// phase 2: part[d][dim] = sum_k o[d][k] * lw[k][dim]   (32 dims, k-loop broadcast)

__device__ inline void addH8(float* acc, const H8& v) {
  #pragma unroll
  for (int q = 0; q < 4; ++q) {
    acc[q * 2 + 0] += __low2float(v.h[q]);
    acc[q * 2 + 1] += __high2float(v.h[q]);
  }
}

__launch_bounds__(256)
__global__ void gather_k(const __half* __restrict__ ysh, const int* __restrict__ rs,
                         const unsigned short* __restrict__ csr, const float* __restrict__ dinv,
                         const float* __restrict__ bias, const float* __restrict__ lw,
                         __half* __restrict__ out, float* __restrict__ part) {
  __shared__ float os[8][256];
  int tid = threadIdx.x;
  int lane = tid & 63;
  int nl = tid >> 5;                  // node 0..7 within block
  int d = blockIdx.x * 8 + nl;
  int c8 = (lane & 31) * 8;

  float acc[8];
  H8 self = *reinterpret_cast<const H8*>(ysh + (size_t)d * 256 + c8);
  #pragma unroll
  for (int q = 0; q < 4; ++q) {
    acc[q * 2 + 0] = __low2float(self.h[q]);
    acc[q * 2 + 1] = __high2float(self.h[q]);
  }

  int e = rs[d], end = rs[d + 1];
  for (; e + 3 < end; e += 4) {
    int s0 = csr[e], s1 = csr[e + 1], s2 = csr[e + 2], s3 = csr[e + 3];
    H8 v0 = *reinterpret_cast<const H8*>(ysh + (size_t)s0 * 256 + c8);
    H8 v1 = *reinterpret_cast<const H8*>(ysh + (size_t)s1 * 256 + c8);
    H8 v2 = *reinterpret_cast<const H8*>(ysh + (size_t)s2 * 256 + c8);
    H8 v3 = *reinterpret_cast<const H8*>(ysh + (size_t)s3 * 256 + c8);
    addH8(acc, v0);
    addH8(acc, v1);
    addH8(acc, v2);
    addH8(acc, v3);
  }
  for (; e < end; ++e) {
    int s0 = csr[e];
    H8 v0 = *reinterpret_cast<const H8*>(ysh + (size_t)s0 * 256 + c8);
    addH8(acc, v0);
  }

  float dv = dinv[d];
  float4 b0 = *reinterpret_cast<const float4*>(bias + c8);
  float4 b1 = *reinterpret_cast<const float4*>(bias + c8 + 4);
  float r0 = fmaxf(acc[0] * dv + b0.x, 0.f);
  float r1 = fmaxf(acc[1] * dv + b0.y, 0.f);
  float r2 = fmaxf(acc[2] * dv + b0.z, 0.f);
  float r3 = fmaxf(acc[3] * dv + b0.w, 0.f);
  float r4 = fmaxf(acc[4] * dv + b1.x, 0.f);
  float r5 = fmaxf(acc[5] * dv + b1.y, 0.f);
  float r6 = fmaxf(acc[6] * dv + b1.z, 0.f);
  float r7 = fmaxf(acc[7] * dv + b1.w, 0.f);
  H8 o;
  o.h[0].x = __float2half_rn(r0); o.h[0].y = __float2half_rn(r1);
  o.h[1].x = __float2half_rn(r2); o.h[1].y = __float2half_rn(r3);
  o.h[2].x = __float2half_rn(r4); o.h[2].y = __float2half_rn(r5);
  o.h[3].x = __float2half_rn(r6); o.h[3].y = __float2half_rn(r7);
  *reinterpret_cast<H8*>(out + (size_t)d * 256 + c8) = o;

  float* dst = &os[nl][c8];
  dst[0] = r0; dst[1] = r1; dst[2] = r2; dst[3] = r3;
  dst[4] = r4; dst[5] = r5; dst[6] = r6; dst[7] = r7;
  __syncthreads();

  // phase 2: thread (a=nl, dim) computes part[d][dim]
  int a = tid >> 5, dim = tid & 31;
  const float4* orow = reinterpret_cast<const float4*>(&os[a][0]);
  float s = 0.f;
  #pragma unroll 16
  for (int k4 = 0; k4 < 64; ++k4) {
    float4 v = orow[k4];
    int k = k4 * 4;
    s += v.x * lw[(k + 0) * 32 + dim];
    s += v.y * lw[(k + 1) * 32 + dim];
    s += v.z * lw[(k + 2) * 32 + dim];
    s += v.w * lw[(k + 3) * 32 + dim];
  }
  part[(size_t)(blockIdx.x * 8 + a) * 32 + dim] = s;
}

// ---------------- fused MLP + readout ----------------

__launch_bounds__(192)
__global__ void mlpfinal_k(const float* __restrict__ p0, const float* __restrict__ p1,
                           const float* __restrict__ p2, const float* __restrict__ p3,
                           const float* __restrict__ p4, const float* __restrict__ p5,
                           const float* __restrict__ action, const float* __restrict__ l1wlast,
                           const float* __restrict__ l1b, const float* __restrict__ l2w,
                           const float* __restrict__ l2b, const float* __restrict__ l3w,
                           const float* __restrict__ l3b, float* __restrict__ out) {
  __shared__ float w2s[1024];
  __shared__ float h1s[6][33];
  __shared__ float red[3];
  int tid = threadIdx.x;
  for (int i = tid; i < 1024; i += 192) w2s[i] = l2w[i];
  int a = tid >> 5, dim = tid & 31;
  int n = blockIdx.x * 6 + a;
  int idx = n * 32 + dim;
  float h1 = l1b[dim] + action[n] * l1wlast[dim]
           + p0[idx] + p1[idx] + p2[idx] + p3[idx] + p4[idx] + p5[idx];
  h1s[a][dim] = fmaxf(h1, 0.f);
  __syncthreads();
  float acc = l2b[dim];
  #pragma unroll
  for (int k = 0; k < 32; ++k) acc += h1s[a][k] * w2s[k * 32 + dim];
  float v = fmaxf(acc, 0.f) * l3w[dim];
  #pragma unroll
  for (int off = 32; off; off >>= 1) v += __shfl_down(v, off, 64);
  int lane = tid & 63, wave = tid >> 6;
  if (lane == 0) red[wave] = v;
  __syncthreads();
  if (tid == 0) out[blockIdx.x] = red[0] + red[1] + red[2] + l3b[0];
}

// ---------------- host ----------------

extern "C" void kernel_launch(void* const* d_in, const int* in_sizes, int n_in,
                              void* d_out, int out_size, void* d_ws, size_t ws_size,
                              hipStream_t stream) {
  const float* state  = (const float*)d_in[0];
  const int*   ei     = (const int*)d_in[1];
  const float* action = (const float*)d_in[2];
  const float* W1 = (const float*)d_in[3];
  const float* b1 = (const float*)d_in[4];
  const float* W2 = (const float*)d_in[5];
  const float* b2 = (const float*)d_in[6];
  const float* W3 = (const float*)d_in[7];
  const float* b3 = (const float*)d_in[8];
  const float* l1w = (const float*)d_in[13];
  const float* l1b = (const float*)d_in[14];
  const float* l2w = (const float*)d_in[15];
  const float* l2b = (const float*)d_in[16];
  const float* l3w = (const float*)d_in[17];
  const float* l3b = (const float*)d_in[18];
  float* out = (float*)d_out;

  char* base = (char*)d_ws;
  size_t off = 0;
  auto carve = [&](size_t bytes) {
    char* q = base + off;
    off += (bytes + 255) & ~(size_t)255;
    return q;
  };
  __half* ysh    = (__half*)carve((size_t)NNODES * 256 * 2);
  __half* obufh  = (__half*)carve((size_t)NNODES * 256 * 2);
  __half* stateh = (__half*)carve((size_t)NNODES * 256 * 2);
  __half* whT1   = (__half*)carve(256 * 256 * 2);
  __half* whT2   = (__half*)carve(256 * 256 * 2);
  __half* whT3   = (__half*)carve(256 * 256 * 2);
  float* parts[6];
  for (int i = 0; i < 6; ++i) parts[i] = (float*)carve((size_t)NNODES * 32 * 4);
  float* dinv  = (float*)carve(NNODES * 4);
  char*  zbase = (char*)carve(0);
  int*   deg   = (int*)carve(NNODES * 4);
  int*   cursor= (int*)carve(NNODES * 4);
  size_t zlen  = (size_t)((char*)carve(0) - zbase);
  int*   rs    = (int*)carve((NNODES + 1) * 4);
  unsigned short* csr = (unsigned short*)carve((size_t)NEDGES * 2);
  int*   bsum  = (int*)carve(256 * 4);

  hipMemsetAsync(zbase, 0, zlen, stream);

  f2hskern_k<<<NNODES / 32, 256, 0, stream>>>(state, l1w + 1280 * 32, stateh, parts[5]);
  wconv3_k<<<256 * 3, 256, 0, stream>>>(W1, W2, W3, whT1, whT2, whT3);

  count_deg_k<<<NEDGES / 256, 256, 0, stream>>>(ei, deg);
  int nb = (NNODES + 255) / 256;
  scan1_k<<<nb, 256, 0, stream>>>(deg, rs, bsum, dinv);
  scan2_k<<<1, 256, 0, stream>>>(bsum, nb);
  scan3_k<<<nb, 256, 0, stream>>>(rs, bsum);
  scatter_k<<<NEDGES / 256, 256, 0, stream>>>(ei, rs, cursor, csr);

  const __half* whTs[5] = {whT1, whT2, whT3, whT3, whT3};
  const float*  bs[5]   = {b1, b2, b3, b3, b3};
  const __half* in = stateh;
  int mblocks = (NNODES + 63) / 64;   // 938
  for (int layer = 0; layer < 5; ++layer) {
    gemm_mfma_k<<<mblocks, 256, 0, stream>>>(in, whTs[layer], dinv, ysh);
    gather_k<<<NNODES / 8, 256, 0, stream>>>(ysh, rs, csr, dinv, bs[layer],
                                             l1w + layer * 256 * 32, obufh, parts[layer]);
    in = obufh;
  }
  mlpfinal_k<<<NGRAPH, 192, 0, stream>>>(parts[0], parts[1], parts[2], parts[3], parts[4],
                                         parts[5], action, l1w + 1536 * 32, l1b, l2w, l2b,
                                         l3w, l3b, out);
}

// Round 8
// 766.063 us; speedup vs baseline: 1.1177x; 1.1177x over previous
//
#include <hip/hip_runtime.h>
#include <hip/hip_fp16.h>

#define NNODES 60000
#define NEDGES 960000
#define NGRAPH 10000

struct __align__(16) H8 { __half2 h[4]; };
struct __align__(8)  H4 { __half2 h[2]; };

typedef _Float16 f16x8 __attribute__((ext_vector_type(8)));
typedef float f32x4 __attribute__((ext_vector_type(4)));

// ---------------- degree / CSR build ----------------

__global__ void count_deg_k(const int* __restrict__ ei, int* __restrict__ deg) {
  int e = blockIdx.x * blockDim.x + threadIdx.x;
  atomicAdd(&deg[ei[NEDGES + e]], 1);
}

__global__ void scan1_k(const int* __restrict__ deg, int* __restrict__ rs,
                        int* __restrict__ bsum, float* __restrict__ dinv) {
  __shared__ int s[256];
  int tid = threadIdx.x;
  int i = blockIdx.x * 256 + tid;
  int v = (i < NNODES) ? deg[i] : 0;
  if (i < NNODES) dinv[i] = rsqrtf((float)v + 1.0f);
  int x = v;
  s[tid] = x; __syncthreads();
  #pragma unroll
  for (int off = 1; off < 256; off <<= 1) {
    int t = (tid >= off) ? s[tid - off] : 0;
    __syncthreads();
    x += t; s[tid] = x; __syncthreads();
  }
  if (i < NNODES) rs[i] = x - v;
  if (tid == 255) bsum[blockIdx.x] = x;
}

__global__ void scan2_k(int* __restrict__ bsum, int nb) {
  __shared__ int s[256];
  int tid = threadIdx.x;
  int v = (tid < nb) ? bsum[tid] : 0;
  int x = v; s[tid] = x; __syncthreads();
  #pragma unroll
  for (int off = 1; off < 256; off <<= 1) {
    int t = (tid >= off) ? s[tid - off] : 0;
    __syncthreads();
    x += t; s[tid] = x; __syncthreads();
  }
  if (tid < nb) bsum[tid] = x - v;
}

__global__ void scan3_k(int* __restrict__ rs, const int* __restrict__ bsum) {
  int i = blockIdx.x * 256 + threadIdx.x;
  if (i < NNODES) rs[i] += bsum[blockIdx.x];
  if (i == 0) rs[NNODES] = NEDGES;
}

__global__ void scatter_k(const int* __restrict__ ei, const int* __restrict__ rs,
                          int* __restrict__ cursor, unsigned short* __restrict__ csr) {
  int e = blockIdx.x * blockDim.x + threadIdx.x;
  int s = ei[e], d = ei[NEDGES + e];
  int pos = rs[d] + atomicAdd(&cursor[d], 1);
  csr[pos] = (unsigned short)s;
}

// ---------------- fused: state fp32->fp16 + p5 = state @ lw6 ----------------

__launch_bounds__(256)
__global__ void f2hskern_k(const float* __restrict__ state, const float* __restrict__ lw,
                           __half* __restrict__ stateh, float* __restrict__ part) {
  __shared__ float os[32][256];
  int tid = threadIdx.x;
  int n0 = blockIdx.x * 32;
  #pragma unroll
  for (int l = 0; l < 4; ++l) {
    int f = tid + l * 256;
    int row = f >> 5, c8 = (f & 31) * 8;
    const float* src = state + (size_t)(n0 + row) * 256 + c8;
    float4 u = *reinterpret_cast<const float4*>(src);
    float4 v = *reinterpret_cast<const float4*>(src + 4);
    float* dst = &os[row][c8];
    dst[0] = u.x; dst[1] = u.y; dst[2] = u.z; dst[3] = u.w;
    dst[4] = v.x; dst[5] = v.y; dst[6] = v.z; dst[7] = v.w;
    H8 o;
    o.h[0].x = __float2half_rn(u.x); o.h[0].y = __float2half_rn(u.y);
    o.h[1].x = __float2half_rn(u.z); o.h[1].y = __float2half_rn(u.w);
    o.h[2].x = __float2half_rn(v.x); o.h[2].y = __float2half_rn(v.y);
    o.h[3].x = __float2half_rn(v.z); o.h[3].y = __float2half_rn(v.w);
    *reinterpret_cast<H8*>(stateh + (size_t)(n0 + row) * 256 + c8) = o;
  }
  __syncthreads();
  int dim = tid & 31, rblk = tid >> 5;
  float a0 = 0.f, a1 = 0.f, a2 = 0.f, a3 = 0.f;
  #pragma unroll 8
  for (int k = 0; k < 256; ++k) {
    float w = lw[k * 32 + dim];
    a0 += os[rblk * 4 + 0][k] * w;
    a1 += os[rblk * 4 + 1][k] * w;
    a2 += os[rblk * 4 + 2][k] * w;
    a3 += os[rblk * 4 + 3][k] * w;
  }
  int base = (n0 + rblk * 4) * 32 + dim;
  part[base] = a0;
  part[base + 32] = a1;
  part[base + 64] = a2;
  part[base + 96] = a3;
}

// ---------------- weight transpose+convert ----------------

__global__ void wconv3_k(const float* __restrict__ W1, const float* __restrict__ W2,
                         const float* __restrict__ W3, __half* __restrict__ T1,
                         __half* __restrict__ T2, __half* __restrict__ T3) {
  int n = blockIdx.x & 255, which = blockIdx.x >> 8, k = threadIdx.x;
  const float* W = which == 0 ? W1 : (which == 1 ? W2 : W3);
  __half* T = which == 0 ? T1 : (which == 1 ? T2 : T3);
  T[n * 256 + k] = __float2half_rn(W[k * 256 + n]);
}

// lwhT[l][dim][k] = fp16(l1w[(l*256+k)*32+dim]) for l=0..4  (grid 160 blocks)
__global__ void wconvL_k(const float* __restrict__ l1w, __half* __restrict__ lwhT) {
  int dimg = blockIdx.x;                 // 0..159: l*32+dim
  int l = dimg >> 5, dim = dimg & 31, k = threadIdx.x;
  lwhT[(size_t)dimg * 256 + k] = __float2half_rn(l1w[((size_t)l * 256 + k) * 32 + dim]);
}

// ---------------- MFMA GEMM + fused skern projection ----------------
// 64x256 tile, A staged once in LDS, B-frags direct from global (L2-hot).
// Extra (when lwhT != null): part[r][0..31] = (A @ lwT)  -- 16 MFMAs/wave.
// Wave layout main: wr=wid>>1 rows 32, wc=wid&1 cols 128. Projection: wave wid
// handles rows wid*16..+16, all 32 dims.

#define LDA 264

__launch_bounds__(256, 3)
__global__ void gemm_mfma_k(const __half* __restrict__ Xh, const __half* __restrict__ WhT,
                            const float* __restrict__ dinv, __half* __restrict__ Y,
                            const __half* __restrict__ lwhT, float* __restrict__ part) {
  __shared__ _Float16 As[64][LDA];
  const int tid = threadIdx.x;
  const int m0 = blockIdx.x * 64;
  const int lane = tid & 63;
  const int wid = tid >> 6;
  const int wr = wid >> 1, wc = wid & 1;
  const int li = lane & 15, lg = lane >> 4;

  #pragma unroll
  for (int l = 0; l < 8; ++l) {
    int f = l * 256 + tid;
    int row = f >> 5, c8 = (f & 31) * 8;
    int gr = m0 + row; if (gr >= NNODES) gr = NNODES - 1;
    *reinterpret_cast<H8*>(&As[row][c8]) =
        *reinterpret_cast<const H8*>(Xh + (size_t)gr * 256 + c8);
  }
  __syncthreads();

  f32x4 acc[2][8];
  #pragma unroll
  for (int i = 0; i < 2; ++i)
    #pragma unroll
    for (int j = 0; j < 8; ++j) acc[i][j] = (f32x4){0.f, 0.f, 0.f, 0.f};

  #pragma unroll
  for (int k0 = 0; k0 < 256; k0 += 32) {
    f16x8 a0 = *reinterpret_cast<const f16x8*>(&As[wr * 32 + li][k0 + lg * 8]);
    f16x8 a1 = *reinterpret_cast<const f16x8*>(&As[wr * 32 + 16 + li][k0 + lg * 8]);
    f16x8 b[8];
    #pragma unroll
    for (int cf = 0; cf < 8; ++cf)
      b[cf] = *reinterpret_cast<const f16x8*>(
          WhT + (size_t)(wc * 128 + cf * 16 + li) * 256 + k0 + lg * 8);
    #pragma unroll
    for (int cf = 0; cf < 8; ++cf) {
      acc[0][cf] = __builtin_amdgcn_mfma_f32_16x16x32_f16(b[cf], a0, acc[0][cf], 0, 0, 0);
      acc[1][cf] = __builtin_amdgcn_mfma_f32_16x16x32_f16(b[cf], a1, acc[1][cf], 0, 0, 0);
    }
  }

  #pragma unroll
  for (int rf = 0; rf < 2; ++rf) {
    int r = m0 + wr * 32 + rf * 16 + li;
    if (r < NNODES) {
      float dv = dinv[r];
      #pragma unroll
      for (int cf = 0; cf < 8; ++cf) {
        int n = wc * 128 + cf * 16 + lg * 4;
        H4 o;
        o.h[0].x = __float2half_rn(acc[rf][cf][0] * dv);
        o.h[0].y = __float2half_rn(acc[rf][cf][1] * dv);
        o.h[1].x = __float2half_rn(acc[rf][cf][2] * dv);
        o.h[1].y = __float2half_rn(acc[rf][cf][3] * dv);
        *reinterpret_cast<H4*>(Y + (size_t)r * 256 + n) = o;
      }
    }
  }

  // fused skern: part[r][dim] = sum_k A[r][k] * lwT[dim][k]; wave wid -> rows wid*16..+16
  if (lwhT != nullptr) {
    f32x4 pacc[2];
    pacc[0] = (f32x4){0.f, 0.f, 0.f, 0.f};
    pacc[1] = (f32x4){0.f, 0.f, 0.f, 0.f};
    #pragma unroll
    for (int k0 = 0; k0 < 256; k0 += 32) {
      f16x8 a = *reinterpret_cast<const f16x8*>(&As[wid * 16 + li][k0 + lg * 8]);
      f16x8 b0 = *reinterpret_cast<const f16x8*>(lwhT + (size_t)li * 256 + k0 + lg * 8);
      f16x8 b1 = *reinterpret_cast<const f16x8*>(lwhT + (size_t)(16 + li) * 256 + k0 + lg * 8);
      pacc[0] = __builtin_amdgcn_mfma_f32_16x16x32_f16(b0, a, pacc[0], 0, 0, 0);
      pacc[1] = __builtin_amdgcn_mfma_f32_16x16x32_f16(b1, a, pacc[1], 0, 0, 0);
    }
    int r = m0 + wid * 16 + li;
    if (r < NNODES) {
      #pragma unroll
      for (int cf = 0; cf < 2; ++cf) {
        float4 v;
        v.x = pacc[cf][0]; v.y = pacc[cf][1]; v.z = pacc[cf][2]; v.w = pacc[cf][3];
        *reinterpret_cast<float4*>(part + (size_t)r * 32 + cf * 16 + lg * 4) = v;
      }
    }
  }
}

// ---------------- gather (r5 proven shape): half-wave per node ----------------

__device__ inline void addH8(float* acc, const H8& v) {
  #pragma unroll
  for (int q = 0; q < 4; ++q) {
    acc[q * 2 + 0] += __low2float(v.h[q]);
    acc[q * 2 + 1] += __high2float(v.h[q]);
  }
}

__global__ void gather_k(const __half* __restrict__ ysh, const int* __restrict__ rs,
                         const unsigned short* __restrict__ csr, const float* __restrict__ dinv,
                         const float* __restrict__ bias, __half* __restrict__ out) {
  int tid = threadIdx.x;
  int lane = tid & 63;
  int wave = (blockIdx.x * blockDim.x + tid) >> 6;
  int d = wave * 2 + (lane >> 5);
  int c8 = (lane & 31) * 8;

  float acc[8];
  H8 self = *reinterpret_cast<const H8*>(ysh + (size_t)d * 256 + c8);
  #pragma unroll
  for (int q = 0; q < 4; ++q) {
    acc[q * 2 + 0] = __low2float(self.h[q]);
    acc[q * 2 + 1] = __high2float(self.h[q]);
  }

  int e = rs[d], end = rs[d + 1];
  for (; e + 3 < end; e += 4) {
    int s0 = csr[e], s1 = csr[e + 1], s2 = csr[e + 2], s3 = csr[e + 3];
    H8 v0 = *reinterpret_cast<const H8*>(ysh + (size_t)s0 * 256 + c8);
    H8 v1 = *reinterpret_cast<const H8*>(ysh + (size_t)s1 * 256 + c8);
    H8 v2 = *reinterpret_cast<const H8*>(ysh + (size_t)s2 * 256 + c8);
    H8 v3 = *reinterpret_cast<const H8*>(ysh + (size_t)s3 * 256 + c8);
    addH8(acc, v0);
    addH8(acc, v1);
    addH8(acc, v2);
    addH8(acc, v3);
  }
  for (; e < end; ++e) {
    int s0 = csr[e];
    H8 v0 = *reinterpret_cast<const H8*>(ysh + (size_t)s0 * 256 + c8);
    addH8(acc, v0);
  }

  float dv = dinv[d];
  float4 b0 = *reinterpret_cast<const float4*>(bias + c8);
  float4 b1 = *reinterpret_cast<const float4*>(bias + c8 + 4);
  float r0 = fmaxf(acc[0] * dv + b0.x, 0.f);
  float r1 = fmaxf(acc[1] * dv + b0.y, 0.f);
  float r2 = fmaxf(acc[2] * dv + b0.z, 0.f);
  float r3 = fmaxf(acc[3] * dv + b0.w, 0.f);
  float r4 = fmaxf(acc[4] * dv + b1.x, 0.f);
  float r5 = fmaxf(acc[5] * dv + b1.y, 0.f);
  float r6 = fmaxf(acc[6] * dv + b1.z, 0.f);
  float r7 = fmaxf(acc[7] * dv + b1.w, 0.f);
  H8 o;
  o.h[0].x = __float2half_rn(r0); o.h[0].y = __float2half_rn(r1);
  o.h[1].x = __float2half_rn(r2); o.h[1].y = __float2half_rn(r3);
  o.h[2].x = __float2half_rn(r4); o.h[2].y = __float2half_rn(r5);
  o.h[3].x = __float2half_rn(r6); o.h[3].y = __float2half_rn(r7);
  *reinterpret_cast<H8*>(out + (size_t)d * 256 + c8) = o;
}

// ---------------- standalone skern (only for o5 -> p4) ----------------

__launch_bounds__(256)
__global__ void skern_k(const __half* __restrict__ in, const float* __restrict__ lw,
                        float* __restrict__ part) {
  __shared__ float os[32][256];
  int tid = threadIdx.x;
  int n0 = blockIdx.x * 32;
  #pragma unroll
  for (int l = 0; l < 4; ++l) {
    int f = tid + l * 256;
    int row = f >> 5, c8 = (f & 31) * 8;
    H8 v = *reinterpret_cast<const H8*>(in + (size_t)(n0 + row) * 256 + c8);
    float* dst = &os[row][c8];
    dst[0] = __low2float(v.h[0]); dst[1] = __high2float(v.h[0]);
    dst[2] = __low2float(v.h[1]); dst[3] = __high2float(v.h[1]);
    dst[4] = __low2float(v.h[2]); dst[5] = __high2float(v.h[2]);
    dst[6] = __low2float(v.h[3]); dst[7] = __high2float(v.h[3]);
  }
  __syncthreads();
  int dim = tid & 31, rblk = tid >> 5;
  float a0 = 0.f, a1 = 0.f, a2 = 0.f, a3 = 0.f;
  #pragma unroll 8
  for (int k = 0; k < 256; ++k) {
    float w = lw[k * 32 + dim];
    a0 += os[rblk * 4 + 0][k] * w;
    a1 += os[rblk * 4 + 1][k] * w;
    a2 += os[rblk * 4 + 2][k] * w;
    a3 += os[rblk * 4 + 3][k] * w;
  }
  int base = (n0 + rblk * 4) * 32 + dim;
  part[base] = a0;
  part[base + 32] = a1;
  part[base + 64] = a2;
  part[base + 96] = a3;
}

// ---------------- fused MLP + readout ----------------

__launch_bounds__(192)
__global__ void mlpfinal_k(const float* __restrict__ p0, const float* __restrict__ p1,
                           const float* __restrict__ p2, const float* __restrict__ p3,
                           const float* __restrict__ p4, const float* __restrict__ p5,
                           const float* __restrict__ action, const float* __restrict__ l1wlast,
                           const float* __restrict__ l1b, const float* __restrict__ l2w,
                           const float* __restrict__ l2b, const float* __restrict__ l3w,
                           const float* __restrict__ l3b, float* __restrict__ out) {
  __shared__ float w2s[1024];
  __shared__ float h1s[6][33];
  __shared__ float red[3];
  int tid = threadIdx.x;
  for (int i = tid; i < 1024; i += 192) w2s[i] = l2w[i];
  int a = tid >> 5, dim = tid & 31;
  int n = blockIdx.x * 6 + a;
  int idx = n * 32 + dim;
  float h1 = l1b[dim] + action[n] * l1wlast[dim]
           + p0[idx] + p1[idx] + p2[idx] + p3[idx] + p4[idx] + p5[idx];
  h1s[a][dim] = fmaxf(h1, 0.f);
  __syncthreads();
  float acc = l2b[dim];
  #pragma unroll
  for (int k = 0; k < 32; ++k) acc += h1s[a][k] * w2s[k * 32 + dim];
  float v = fmaxf(acc, 0.f) * l3w[dim];
  #pragma unroll
  for (int off = 32; off; off >>= 1) v += __shfl_down(v, off, 64);
  int lane = tid & 63, wave = tid >> 6;
  if (lane == 0) red[wave] = v;
  __syncthreads();
  if (tid == 0) out[blockIdx.x] = red[0] + red[1] + red[2] + l3b[0];
}

// ---------------- host ----------------

extern "C" void kernel_launch(void* const* d_in, const int* in_sizes, int n_in,
                              void* d_out, int out_size, void* d_ws, size_t ws_size,
                              hipStream_t stream) {
  const float* state  = (const float*)d_in[0];
  const int*   ei     = (const int*)d_in[1];
  const float* action = (const float*)d_in[2];
  const float* W1 = (const float*)d_in[3];
  const float* b1 = (const float*)d_in[4];
  const float* W2 = (const float*)d_in[5];
  const float* b2 = (const float*)d_in[6];
  const float* W3 = (const float*)d_in[7];
  const float* b3 = (const float*)d_in[8];
  const float* l1w = (const float*)d_in[13];
  const float* l1b = (const float*)d_in[14];
  const float* l2w = (const float*)d_in[15];
  const float* l2b = (const float*)d_in[16];
  const float* l3w = (const float*)d_in[17];
  const float* l3b = (const float*)d_in[18];
  float* out = (float*)d_out;

  char* base = (char*)d_ws;
  size_t off = 0;
  auto carve = [&](size_t bytes) {
    char* q = base + off;
    off += (bytes + 255) & ~(size_t)255;
    return q;
  };
  __half* ysh    = (__half*)carve((size_t)NNODES * 256 * 2);
  __half* obufh  = (__half*)carve((size_t)NNODES * 256 * 2);
  __half* stateh = (__half*)carve((size_t)NNODES * 256 * 2);
  __half* whT1   = (__half*)carve(256 * 256 * 2);
  __half* whT2   = (__half*)carve(256 * 256 * 2);
  __half* whT3   = (__half*)carve(256 * 256 * 2);
  __half* lwhT   = (__half*)carve(5 * 32 * 256 * 2);   // [l][dim][k]
  float* parts[6];
  for (int i = 0; i < 6; ++i) parts[i] = (float*)carve((size_t)NNODES * 32 * 4);
  float* dinv  = (float*)carve(NNODES * 4);
  char*  zbase = (char*)carve(0);
  int*   deg   = (int*)carve(NNODES * 4);
  int*   cursor= (int*)carve(NNODES * 4);
  size_t zlen  = (size_t)((char*)carve(0) - zbase);
  int*   rs    = (int*)carve((NNODES + 1) * 4);
  unsigned short* csr = (unsigned short*)carve((size_t)NEDGES * 2);
  int*   bsum  = (int*)carve(256 * 4);

  hipMemsetAsync(zbase, 0, zlen, stream);

  f2hskern_k<<<NNODES / 32, 256, 0, stream>>>(state, l1w + 1280 * 32, stateh, parts[5]);
  wconv3_k<<<256 * 3, 256, 0, stream>>>(W1, W2, W3, whT1, whT2, whT3);
  wconvL_k<<<160, 256, 0, stream>>>(l1w, lwhT);

  count_deg_k<<<NEDGES / 256, 256, 0, stream>>>(ei, deg);
  int nb = (NNODES + 255) / 256;
  scan1_k<<<nb, 256, 0, stream>>>(deg, rs, bsum, dinv);
  scan2_k<<<1, 256, 0, stream>>>(bsum, nb);
  scan3_k<<<nb, 256, 0, stream>>>(rs, bsum);
  scatter_k<<<NEDGES / 256, 256, 0, stream>>>(ei, rs, cursor, csr);

  const __half* whTs[5] = {whT1, whT2, whT3, whT3, whT3};
  const float*  bs[5]   = {b1, b2, b3, b3, b3};
  const __half* in = stateh;
  int mblocks = (NNODES + 63) / 64;   // 938
  for (int layer = 0; layer < 5; ++layer) {
    // gemm layer `layer` consumes o_{layer} (or state); fused projection computes
    // parts[layer-1] from its A-tile (skip for layer 0: state handled in f2hskern).
    const __half* plw = (layer == 0) ? nullptr : lwhT + (size_t)(layer - 1) * 32 * 256;
    float* ppart = (layer == 0) ? nullptr : parts[layer - 1];
    gemm_mfma_k<<<mblocks, 256, 0, stream>>>(in, whTs[layer], dinv, ysh, plw, ppart);
    gather_k<<<NNODES / 8, 256, 0, stream>>>(ysh, rs, csr, dinv, bs[layer], obufh);
    in = obufh;
  }
  // o5 -> p4
  skern_k<<<NNODES / 32, 256, 0, stream>>>(obufh, l1w + 1024 * 32, parts[4]);
  mlpfinal_k<<<NGRAPH, 192, 0, stream>>>(parts[0], parts[1], parts[2], parts[3], parts[4],
                                         parts[5], action, l1w + 1536 * 32, l1b, l2w, l2b,
                                         l3w, l3b, out);
}